// Round 10
// baseline (94.215 us; speedup 1.0000x reference)
//
#include <hip/hip_runtime.h>
#include <math.h>

// ROIAlign FPN, LDS row-staged (tight window) with block-uniform fallback.
// Block = (proposal n, channel-quarter cs), 256 threads = 16x16 sample grid.
// If the ROI's tap window fits 32x32 (true unless extreme aspect ratio),
// stage 4 channels' windows into LDS (2 rows x 32 cols per wave-load,
// coalesced, each unique line fetched once), consume taps from LDS.
// Else: round-7 verified direct-gather path. Grid = 4096 blocks.

#define CSPLIT 4
#define CPB (256 / CSPLIT)      // 64 channels per block
#define WROW 33                 // padded LDS row stride (bank spread)
#define CHSLOT (32 * WROW)      // 1056 floats per channel slot

__global__ __launch_bounds__(256) void roialign_rowstage_kernel(
    const float* __restrict__ f0, const float* __restrict__ f1,
    const float* __restrict__ f2, const float* __restrict__ f3,
    const float* __restrict__ props, float* __restrict__ out)
{
    __shared__ float S[4 * CHSLOT];   // 16896 B

    const int blk = blockIdx.x;          // n*CSPLIT + cs
    const int cs  = blk & (CSPLIT - 1);
    const int n   = blk >> 2;            // 0..1023
    const int b   = n >> 9;              // image 0..1

    const int tid  = threadIdx.x;
    const int lane = tid & 63;
    const int sx   = tid & 15;
    const int sy   = tid >> 4;
    const float rx = (float)min(sx, 13);
    const float ry = (float)min(sy, 13);

    // proposal (block-uniform)
    const float px1 = props[n * 4 + 0];
    const float py1 = props[n * 4 + 1];
    const float px2 = props[n * 4 + 2];
    const float py2 = props[n * 4 + 3];
    const float area = (px2 - px1) * (py2 - py1);
    float lf = floorf(2.0f + log2f(sqrtf(area) / 224.0f));
    lf = fminf(fmaxf(lf, 0.0f), 3.0f);
    const int lvl = (int)lf;

    const float* feat;
    int W;
    float scale;
    if (lvl == 0)      { feat = f0; W = 256; scale = 0.25f;    }
    else if (lvl == 1) { feat = f1; W = 128; scale = 0.125f;   }
    else if (lvl == 2) { feat = f2; W = 64;  scale = 0.0625f;  }
    else               { feat = f3; W = 32;  scale = 0.03125f; }

    // scaled proposal + sampling units (identical expressions to prior rounds)
    const float sx1f = px1 * scale;
    const float sy1f = py1 * scale;
    const float sx2f = px2 * scale;
    const float sy2f = py2 * scale;
    const float w_unit = (sx2f - sx1f) / 14.0f;
    const float h_unit = (sy2f - sy1f) / 14.0f;
    const float Wm1 = (float)(W - 1);

    // per-thread x geometry
    const float fx = rx * w_unit + w_unit * 0.5f + sx1f;
    int x0 = (int)floorf(fx);
    const float xc = fminf(fmaxf(fx, 0.0f), Wm1);
    int x0c = min(max(x0, 0), W - 1);
    int x1c = min(max(x0 + 1, 0), W - 1);
    const float wx0 = (float)x1c - xc;
    const float wx1 = xc - (float)x0c;
    const int xv = min(x0c, W - 2);

    // per-thread y geometry
    const float fy = ry * h_unit + h_unit * 0.5f + sy1f;
    int y0 = (int)floorf(fy);
    const float yc = fminf(fmaxf(fy, 0.0f), Wm1);
    int y0c = min(max(y0, 0), W - 1);
    int y1c = min(max(y0 + 1, 0), W - 1);
    const float wy0 = (float)y1c - yc;
    const float wy1 = yc - (float)y0c;

    // block-uniform tap-window bounds (same formulas at corner samples;
    // geometry is monotone in rx/ry so every thread's taps fall inside)
    const float fx_0  = 0.0f  * w_unit + w_unit * 0.5f + sx1f;
    const float fx_13 = 13.0f * w_unit + w_unit * 0.5f + sx1f;
    const int xv0  = min(min(max((int)floorf(fx_0),  0), W - 1), W - 2);
    const int xv13 = min(min(max((int)floorf(fx_13), 0), W - 1), W - 2);
    const int w_win = xv13 - xv0 + 2;              // cols xv0 .. xv13+1
    const float fy_0  = 0.0f  * h_unit + h_unit * 0.5f + sy1f;
    const float fy_13 = 13.0f * h_unit + h_unit * 0.5f + sy1f;
    const int ymin = min(max((int)floorf(fy_0), 0), W - 1);
    const int ymax = min(max((int)floorf(fy_13) + 1, 0), W - 1);
    const int h_win = ymax - ymin + 1;
    const bool stageable = (w_win <= 32) && (h_win <= 32);

    const int WW = W * W;
    const int c0 = cs * CPB;
    const float* fb = feat + ((size_t)b * 256 + (size_t)c0) * (size_t)WW;

    const bool active = (((sx | sy) & 1) == 0) && sx < 14 && sy < 14;
    float* outp = out + (size_t)(n * 256 + c0) * 49
                      + (size_t)(sy >> 1) * 7 + (size_t)(sx >> 1);

    if (stageable) {
        // LDS tap offsets (channel-invariant)
        const int loff00 = (y0c - ymin) * WROW + (xv - xv0);
        const int loff10 = (y1c - ymin) * WROW + (xv - xv0);
        const int ch_s = tid >> 6;                 // this wave stages ch_s
        const int r_half = lane >> 5;              // 0 or 1
        const int col = lane & 31;
        const int col_g = min(xv0 + col, W - 1);   // clamp stays in this row
        const float* fwin = fb + (size_t)ymin * (size_t)W;

        for (int cb = 0; cb < CPB; cb += 4) {
            // stage 4 channels: wave w loads channel cb+w, 2 rows x 32 cols/iter
            {
                const float* src = fwin + (size_t)(cb + ch_s) * (size_t)WW;
                float* dst = S + ch_s * CHSLOT;
                for (int r = r_half; r < h_win; r += 2)
                    dst[r * WROW + col] = src[(size_t)r * (size_t)W + col_g];
            }
            __syncthreads();

            #pragma unroll
            for (int j = 0; j < 4; ++j) {
                const int base = j * CHSLOT;
                const float a0 = S[base + loff00];
                const float a1 = S[base + loff00 + 1];
                const float b0 = S[base + loff10];
                const float b1 = S[base + loff10 + 1];
                float v = wy0 * (wx0 * a0 + wx1 * a1)
                        + wy1 * (wx0 * b0 + wx1 * b1);
                v = fmaxf(v, __shfl_xor(v, 1));
                v = fmaxf(v, __shfl_xor(v, 16));
                if (active) outp[(size_t)(cb + j) * 49] = v;
            }
            __syncthreads();
        }
    } else {
        // fallback: round-7 verified direct float2 gathers
        const int off00 = y0c * W + xv;
        const int off10 = y1c * W + xv;
        #pragma unroll 4
        for (int c = 0; c < CPB; ++c) {
            const float* p = fb + (size_t)c * (size_t)WW;
            const float2 a  = *reinterpret_cast<const float2*>(p + off00);
            const float2 bb = *reinterpret_cast<const float2*>(p + off10);
            float v = wy0 * (wx0 * a.x  + wx1 * a.y)
                    + wy1 * (wx0 * bb.x + wx1 * bb.y);
            v = fmaxf(v, __shfl_xor(v, 1));
            v = fmaxf(v, __shfl_xor(v, 16));
            if (active) outp[(size_t)c * 49] = v;
        }
    }
}

extern "C" void kernel_launch(void* const* d_in, const int* in_sizes, int n_in,
                              void* d_out, int out_size, void* d_ws, size_t ws_size,
                              hipStream_t stream) {
    const float* f0 = (const float*)d_in[0];
    const float* f1 = (const float*)d_in[1];
    const float* f2 = (const float*)d_in[2];
    const float* f3 = (const float*)d_in[3];
    const float* props = (const float*)d_in[4];
    float* out = (float*)d_out;

    dim3 grid(1024 * CSPLIT), block(256);
    hipLaunchKernelGGL(roialign_rowstage_kernel, grid, block, 0, stream,
                       f0, f1, f2, f3, props, out);
}

// Round 12
// 88.983 us; speedup vs baseline: 1.0588x; 1.0588x over previous
//
#include <hip/hip_runtime.h>
#include <math.h>

// ROIAlign FPN, register-pipelined LDS staging (exact-width) + fallback.
// Block = (proposal n, channel-quarter cs), 256 threads = 16x16 sample grid.
// Stageable (w_win<=32 && h_win<=32): per phase, each wave stages one
// channel's window via a 16-deep predicated register batch (all loads in
// flight before any ds_write), exact w_win columns only; consume from LDS.
// Non-stageable (extreme aspect): round-7 direct float2 gathers.
// Grid = 4096 blocks. LDS 16896 B.

#define CSPLIT 4
#define CPB (256 / CSPLIT)      // 64 channels per block
#define SLOT 1056               // 32 rows x 33 padded cols (max window)
#define CHP 4                   // channels per phase = waves per block

__global__ __launch_bounds__(256) void roialign_pipestage_kernel(
    const float* __restrict__ f0, const float* __restrict__ f1,
    const float* __restrict__ f2, const float* __restrict__ f3,
    const float* __restrict__ props, float* __restrict__ out)
{
    __shared__ float S[CHP * SLOT];   // 16896 B

    const int blk = blockIdx.x;          // n*CSPLIT + cs
    const int cs  = blk & (CSPLIT - 1);
    const int n   = blk >> 2;            // 0..1023
    const int b   = n >> 9;              // image 0..1

    const int tid  = threadIdx.x;
    const int lane = tid & 63;
    const int wv   = tid >> 6;
    const int sx   = tid & 15;
    const int sy   = tid >> 4;
    const float rx = (float)min(sx, 13);
    const float ry = (float)min(sy, 13);

    // proposal (block-uniform)
    const float px1 = props[n * 4 + 0];
    const float py1 = props[n * 4 + 1];
    const float px2 = props[n * 4 + 2];
    const float py2 = props[n * 4 + 3];
    const float area = (px2 - px1) * (py2 - py1);
    float lf = floorf(2.0f + log2f(sqrtf(area) / 224.0f));
    lf = fminf(fmaxf(lf, 0.0f), 3.0f);
    const int lvl = (int)lf;

    const float* feat;
    int W;
    float scale;
    if (lvl == 0)      { feat = f0; W = 256; scale = 0.25f;    }
    else if (lvl == 1) { feat = f1; W = 128; scale = 0.125f;   }
    else if (lvl == 2) { feat = f2; W = 64;  scale = 0.0625f;  }
    else               { feat = f3; W = 32;  scale = 0.03125f; }

    // scaled proposal + sampling units (identical expressions to prior rounds)
    const float sx1f = px1 * scale;
    const float sy1f = py1 * scale;
    const float sx2f = px2 * scale;
    const float sy2f = py2 * scale;
    const float w_unit = (sx2f - sx1f) / 14.0f;
    const float h_unit = (sy2f - sy1f) / 14.0f;
    const float Wm1 = (float)(W - 1);

    // per-thread x geometry
    const float fx = rx * w_unit + w_unit * 0.5f + sx1f;
    int x0 = (int)floorf(fx);
    const float xc = fminf(fmaxf(fx, 0.0f), Wm1);
    int x0c = min(max(x0, 0), W - 1);
    int x1c = min(max(x0 + 1, 0), W - 1);
    const float wx0 = (float)x1c - xc;
    const float wx1 = xc - (float)x0c;
    const int xv = min(x0c, W - 2);

    // per-thread y geometry
    const float fy = ry * h_unit + h_unit * 0.5f + sy1f;
    int y0 = (int)floorf(fy);
    const float yc = fminf(fmaxf(fy, 0.0f), Wm1);
    int y0c = min(max(y0, 0), W - 1);
    int y1c = min(max(y0 + 1, 0), W - 1);
    const float wy0 = (float)y1c - yc;
    const float wy1 = yc - (float)y0c;

    // block-uniform tap-window bounds (corner samples; geometry monotone)
    const float fx_0  = 0.0f  * w_unit + w_unit * 0.5f + sx1f;
    const float fx_13 = 13.0f * w_unit + w_unit * 0.5f + sx1f;
    const int xv0  = min(min(max((int)floorf(fx_0),  0), W - 1), W - 2);
    const int xv13 = min(min(max((int)floorf(fx_13), 0), W - 1), W - 2);
    const int w_win = xv13 - xv0 + 2;              // cols xv0 .. xv13+1
    const float fy_0  = 0.0f  * h_unit + h_unit * 0.5f + sy1f;
    const float fy_13 = 13.0f * h_unit + h_unit * 0.5f + sy1f;
    const int ymin = min(max((int)floorf(fy_0), 0), W - 1);
    const int ymax = min(max((int)floorf(fy_13) + 1, 0), W - 1);
    const int h_win = ymax - ymin + 1;
    const bool stageable = (w_win <= 32) && (h_win <= 32);

    const int WW = W * W;
    const int c0 = cs * CPB;
    const float* fb = feat + ((size_t)b * 256 + (size_t)c0) * (size_t)WW;

    const bool active = (((sx | sy) & 1) == 0) && sx < 14 && sy < 14;
    float* outp = out + (size_t)(n * 256 + c0) * 49
                      + (size_t)(sy >> 1) * 7 + (size_t)(sx >> 1);

    if (stageable) {
        const int w_pad  = w_win | 1;              // odd row stride
        const int loff00 = (y0c - ymin) * w_pad + (xv - xv0);
        const int loff10 = (y1c - ymin) * w_pad + (xv - xv0);
        const int cload  = lane & 31;              // col within window
        const int rhalf  = lane >> 5;              // 0 or 1
        const bool cok   = cload < w_win;
        const float* fwin = fb + (size_t)ymin * (size_t)W + (size_t)xv0;

        for (int cb = 0; cb < CPB; cb += CHP) {
            // ---- stage: wave wv stages channel cb+wv, 16-deep reg batch ----
            const float* src = fwin + (size_t)(cb + wv) * (size_t)WW;
            float* dst = S + wv * SLOT;
            float t[16];
            #pragma unroll
            for (int k = 0; k < 16; ++k) {
                const int r = rhalf + 2 * k;
                t[k] = (cok && r < h_win)
                     ? src[(size_t)r * (size_t)W + (size_t)cload] : 0.0f;
            }
            #pragma unroll
            for (int k = 0; k < 16; ++k) {
                const int r = rhalf + 2 * k;
                if (cok && r < h_win) dst[r * w_pad + cload] = t[k];
            }
            __syncthreads();

            // ---- consume 4 channels from LDS ----
            #pragma unroll
            for (int j = 0; j < CHP; ++j) {
                const int base = j * SLOT;
                const float a0 = S[base + loff00];
                const float a1 = S[base + loff00 + 1];
                const float b0 = S[base + loff10];
                const float b1 = S[base + loff10 + 1];
                float v = wy0 * (wx0 * a0 + wx1 * a1)
                        + wy1 * (wx0 * b0 + wx1 * b1);
                v = fmaxf(v, __shfl_xor(v, 1));
                v = fmaxf(v, __shfl_xor(v, 16));
                if (active) outp[(size_t)(cb + j) * 49] = v;
            }
            __syncthreads();
        }
    } else {
        // fallback: round-7 verified direct float2 gathers
        const int off00 = y0c * W + xv;
        const int off10 = y1c * W + xv;
        #pragma unroll 4
        for (int c = 0; c < CPB; ++c) {
            const float* p = fb + (size_t)c * (size_t)WW;
            const float2 a  = *reinterpret_cast<const float2*>(p + off00);
            const float2 bb = *reinterpret_cast<const float2*>(p + off10);
            float v = wy0 * (wx0 * a.x  + wx1 * a.y)
                    + wy1 * (wx0 * bb.x + wx1 * bb.y);
            v = fmaxf(v, __shfl_xor(v, 1));
            v = fmaxf(v, __shfl_xor(v, 16));
            if (active) outp[(size_t)c * 49] = v;
        }
    }
}

extern "C" void kernel_launch(void* const* d_in, const int* in_sizes, int n_in,
                              void* d_out, int out_size, void* d_ws, size_t ws_size,
                              hipStream_t stream) {
    const float* f0 = (const float*)d_in[0];
    const float* f1 = (const float*)d_in[1];
    const float* f2 = (const float*)d_in[2];
    const float* f3 = (const float*)d_in[3];
    const float* props = (const float*)d_in[4];
    float* out = (float*)d_out;

    dim3 grid(1024 * CSPLIT), block(256);
    hipLaunchKernelGGL(roialign_pipestage_kernel, grid, block, 0, stream,
                       f0, f1, f2, f3, props, out);
}

// Round 13
// 74.945 us; speedup vs baseline: 1.2571x; 1.1873x over previous
//
#include <hip/hip_runtime.h>
#include <math.h>

// ROIAlign FPN, channel-loop layout, explicit 8-wide load batching.
// (Round-9 verified best: 74.9 us.)
// Block = (proposal n, channel-eighth cs): 256 threads = 16x16 padded sample
// grid (14x14 active). Geometry computed once per thread; channel loop in
// batches of 8: issue 16 float2 gathers, then consume (bilinear + shfl-pool
// + predicated store). Grid = 1024 * 8 = 8192 blocks.
//
// Why this shape: bound is TA/L1 line-service throughput. L1/MSHR already
// merges same-line requests within the instruction window, so the direct
// gather stream is ~unique-line-optimal; LDS staging variants (r8/r10/r12)
// all added more overhead than they deduplicated, and instruction-packing
// changes (r7/r9) are neutral.

#define CSPLIT 8
#define CPB (256 / CSPLIT)   // channels per block = 32
#define BATCH 8

__global__ __launch_bounds__(256) void roialign_chan_kernel(
    const float* __restrict__ f0, const float* __restrict__ f1,
    const float* __restrict__ f2, const float* __restrict__ f3,
    const float* __restrict__ props, float* __restrict__ out)
{
    const int blk = blockIdx.x;          // n*CSPLIT + cs
    const int cs  = blk & (CSPLIT - 1);
    const int n   = blk >> 3;            // 0..1023
    const int b   = n >> 9;              // image 0..1

    const int tid = threadIdx.x;
    const int sx  = tid & 15;            // sample col 0..15 (14 active)
    const int sy  = tid >> 4;            // sample row 0..15 (14 active)
    const float rx = (float)min(sx, 13);
    const float ry = (float)min(sy, 13);

    // proposal (block-uniform -> scalar path)
    const float px1 = props[n * 4 + 0];
    const float py1 = props[n * 4 + 1];
    const float px2 = props[n * 4 + 2];
    const float py2 = props[n * 4 + 3];
    const float area = (px2 - px1) * (py2 - py1);
    float lf = floorf(2.0f + log2f(sqrtf(area) / 224.0f));
    lf = fminf(fmaxf(lf, 0.0f), 3.0f);
    const int lvl = (int)lf;

    const float* feat;
    int W;
    float scale;
    if (lvl == 0)      { feat = f0; W = 256; scale = 0.25f;    }
    else if (lvl == 1) { feat = f1; W = 128; scale = 0.125f;   }
    else if (lvl == 2) { feat = f2; W = 64;  scale = 0.0625f;  }
    else               { feat = f3; W = 32;  scale = 0.03125f; }

    // scaled proposal + sampling units (identical expressions to prior rounds)
    const float sx1f = px1 * scale;
    const float sy1f = py1 * scale;
    const float sx2f = px2 * scale;
    const float sy2f = py2 * scale;
    const float w_unit = (sx2f - sx1f) / 14.0f;
    const float h_unit = (sy2f - sy1f) / 14.0f;
    const float Wm1 = (float)(W - 1);

    // x geometry
    const float fx = rx * w_unit + w_unit * 0.5f + sx1f;
    int x0 = (int)floorf(fx);
    const float xc = fminf(fmaxf(fx, 0.0f), Wm1);
    int x0c = min(max(x0, 0), W - 1);
    int x1c = min(max(x0 + 1, 0), W - 1);
    const float wx0 = (float)x1c - xc;
    const float wx1 = xc - (float)x0c;
    const int xv = min(x0c, W - 2);      // when x0c==W-1 both weights are 0

    // y geometry
    const float fy = ry * h_unit + h_unit * 0.5f + sy1f;
    int y0 = (int)floorf(fy);
    const float yc = fminf(fmaxf(fy, 0.0f), Wm1);
    int y0c = min(max(y0, 0), W - 1);
    int y1c = min(max(y0 + 1, 0), W - 1);
    const float wy0 = (float)y1c - yc;
    const float wy1 = yc - (float)y0c;

    // per-lane tap offsets (channel-invariant), 32-bit
    const int off00 = y0c * W + xv;      // row y0c, cols xv, xv+1
    const int off10 = y1c * W + xv;      // row y1c
    const int WW = W * W;

    const int c0 = cs * CPB;
    const float* fb = feat + ((size_t)b * 256 + (size_t)c0) * (size_t)WW;

    const bool active = (((sx | sy) & 1) == 0) && sx < 14 && sy < 14;
    float* outp = out + (size_t)(n * 256 + c0) * 49
                      + (size_t)(sy >> 1) * 7 + (size_t)(sx >> 1);

    for (int cb = 0; cb < CPB; cb += BATCH) {
        float2 A[BATCH], Bv[BATCH];
        // phase 1: issue all 16 loads (no consumer between them)
        #pragma unroll
        for (int k = 0; k < BATCH; ++k) {
            const float* p = fb + (size_t)(cb + k) * (size_t)WW;
            A[k]  = *reinterpret_cast<const float2*>(p + off00);
            Bv[k] = *reinterpret_cast<const float2*>(p + off10);
        }
        // phase 2: consume
        #pragma unroll
        for (int k = 0; k < BATCH; ++k) {
            float v = wy0 * (wx0 * A[k].x  + wx1 * A[k].y)
                    + wy1 * (wx0 * Bv[k].x + wx1 * Bv[k].y);
            v = fmaxf(v, __shfl_xor(v, 1));    // sx pair
            v = fmaxf(v, __shfl_xor(v, 16));   // sy pair
            if (active) outp[(size_t)(cb + k) * 49] = v;
        }
    }
}

extern "C" void kernel_launch(void* const* d_in, const int* in_sizes, int n_in,
                              void* d_out, int out_size, void* d_ws, size_t ws_size,
                              hipStream_t stream) {
    const float* f0 = (const float*)d_in[0];
    const float* f1 = (const float*)d_in[1];
    const float* f2 = (const float*)d_in[2];
    const float* f3 = (const float*)d_in[3];
    const float* props = (const float*)d_in[4];
    float* out = (float*)d_out;

    dim3 grid(1024 * CSPLIT), block(256);
    hipLaunchKernelGGL(roialign_chan_kernel, grid, block, 0, stream,
                       f0, f1, f2, f3, props, out);
}